// Round 12
// baseline (231.627 us; speedup 1.0000x reference)
//
#include <hip/hip_runtime.h>
#include <math.h>

#define B_  2
#define L_  2048
#define D_  1024
#define H_  16
#define DH_ 64
#define E3D 3072
#define LN_EPS 1e-5f

typedef unsigned short u16;
typedef __attribute__((ext_vector_type(8))) short bf16x8;
typedef __attribute__((ext_vector_type(4))) float f32x4;

// pack two fp32 -> packed bf16 pair (round-half-up) via v_perm_b32
__device__ inline unsigned pack2(float lo, float hi) {
    unsigned a = __builtin_bit_cast(unsigned, lo) + 0x8000u;
    unsigned b = __builtin_bit_cast(unsigned, hi) + 0x8000u;
    return __builtin_amdgcn_perm(b, a, 0x07060302);
}
// truncating variant (1 op): used ONLY for P in the attention softmax.
// p feeds numerator (PV) and denominator (ones-row l) with the same bits,
// so the downward truncation bias cancels to first order in O = PV/l.
__device__ inline unsigned pack2t(float lo, float hi) {
    return __builtin_amdgcn_perm(__builtin_bit_cast(unsigned, hi),
                                 __builtin_bit_cast(unsigned, lo), 0x07060302);
}
__device__ inline float bf2f(u16 v) {
    return __builtin_bit_cast(float, (unsigned)v << 16);
}
__device__ inline void async16(const void* g, void* l) {
    __builtin_amdgcn_global_load_lds(
        (const __attribute__((address_space(1))) unsigned*)g,
        (__attribute__((address_space(3))) unsigned*)l, 16, 0, 0);
}

// log2(e) folded into Q scale so softmax uses raw v_exp_f32 (exp2)
#define QSCALE (0.125f * 1.44269504088896f)

// ---------------------------------------------------------------------------
// fused f32 -> bf16 conversion of x (2048 blk) / in_w (1536 blk) / out_w (512)
// ---------------------------------------------------------------------------
__global__ __launch_bounds__(256) void cvt_all(
    const float* __restrict__ x, const float* __restrict__ iw,
    const float* __restrict__ ow, u16* __restrict__ xb,
    u16* __restrict__ iwb, u16* __restrict__ owb)
{
    const int bid = blockIdx.x;
    const float* src; u16* dst; int base;
    if (bid < 2048)      { src = x;  dst = xb;  base = bid * 2048; }
    else if (bid < 3584) { src = iw; dst = iwb; base = (bid - 2048) * 2048; }
    else                 { src = ow; dst = owb; base = (bid - 3584) * 2048; }
    const int i = base + threadIdx.x * 8;
    float4 v0 = *(const float4*)(src + i);
    float4 v1 = *(const float4*)(src + i + 4);
    uint4 w;
    w.x = pack2(v0.x, v0.y); w.y = pack2(v0.z, v0.w);
    w.z = pack2(v1.x, v1.y); w.w = pack2(v1.z, v1.w);
    *(uint4*)(dst + i) = w;
}

// ---------------------------------------------------------------------------
// bf16 MFMA NT-GEMM: C = A * W^T + bias, bf16 out.  A: MxK, W: NxK (bf16).
// Template MT = M-tile (128 or 64); N-tile fixed 128. BK=32.
//  MT=64 now used for BOTH GEMMs: QKV grid 24x64 = 1536 blocks = 6 blk/CU
//  (128-tile gave 3/CU -> barrier drains exposed), out-proj 8x64 = 512 = 2/CU.
// Operands swapped (mfma(wf, af)) -> lane owns 4 consecutive cols.
// Epilogue: bf16 -> LDS (68-word padded rows) -> lane-contiguous uint4 stores.
// NOTE: acc[][] only indexed with compile-time constants (R6 scratch lesson).
// cols < qlimit scaled by QSCALE (attention scale + log2e folded).
// ---------------------------------------------------------------------------
template<int MT>
__global__ __launch_bounds__(256) void gemm_bf16(
    const u16* __restrict__ A, const u16* __restrict__ W,
    const float* __restrict__ bias, u16* __restrict__ outB,
    int M, int N, int K, int qlimit)
{
    constexpr int WC    = (MT == 128) ? 4 : 2;          // col subtiles per wave
    constexpr int SMEMB = (MT == 128) ? 34816 : 17408;  // max(staging, epilogue)
    __shared__ __align__(16) char smem[SMEMB];
    u16* As = (u16*)smem;                 // MT x 32
    u16* Ws = As + MT * 32;               // 128 x 32

    const int t    = threadIdx.x;
    const int wave = t >> 6;
    const int lane = t & 63;
    const int a    = lane & 15;
    const int g    = lane >> 4;
    const int row0 = blockIdx.y * MT;
    const int col0 = blockIdx.x * 128;

    const int srowA = wave * (MT / 4) + (lane >> 2);
    const int srowW = wave * 32 + (lane >> 2);
    const int sseg  = (lane & 3) * 8;
    const u16* Ag = A + (size_t)(row0 + srowA) * K + sseg;
    const u16* Wg = W + (size_t)(col0 + srowW) * K + sseg;
    u16* AsW = &As[wave * (MT / 4) * 32];
    u16* WsW = &Ws[wave * 32 * 32];

    f32x4 acc[4][WC];
    #pragma unroll
    for (int i = 0; i < 4; ++i)
        #pragma unroll
        for (int j = 0; j < WC; ++j)
            acc[i][j] = (f32x4){0.f, 0.f, 0.f, 0.f};

    const int ar = (MT == 128) ? (wave & 1) * 64 : 0;
    const int wc = (MT == 128) ? (wave >> 1) * 64 : wave * 32;

    for (int kt = 0; kt < K; kt += 32) {
        __syncthreads();
        if (MT == 128) {
            async16(Ag + kt,                  AsW);
            async16(Ag + (size_t)16 * K + kt, AsW + 16 * 32);
        } else {
            async16(Ag + kt, AsW);   // 16 rows/wave: exactly one instruction
        }
        async16(Wg + kt,                  WsW);
        async16(Wg + (size_t)16 * K + kt, WsW + 16 * 32);
        __syncthreads();

        bf16x8 af[4], wf[WC];
        #pragma unroll
        for (int i = 0; i < 4; ++i)
            af[i] = *(const bf16x8*)&As[(ar + i * 16 + a) * 32 + g * 8];
        #pragma unroll
        for (int j = 0; j < WC; ++j)
            wf[j] = *(const bf16x8*)&Ws[(wc + j * 16 + a) * 32 + g * 8];
        #pragma unroll
        for (int i = 0; i < 4; ++i)
            #pragma unroll
            for (int j = 0; j < WC; ++j)
                acc[i][j] = __builtin_amdgcn_mfma_f32_16x16x32_bf16(
                    wf[j], af[i], acc[i][j], 0, 0, 0);
    }

    // ---- epilogue: acc -> LDS (constant indices only) -> coalesced stores
    const float s = (col0 < qlimit) ? QSCALE : 1.0f;
    __syncthreads();                      // staging reads done; reuse smem
    unsigned* Cs = (unsigned*)smem;       // MT rows x 68 words (64 data + pad)
    #pragma unroll
    for (int j = 0; j < WC; ++j) {
        const int cb = wc + j * 16 + g * 4;
        const float4 bj = *(const float4*)(bias + col0 + cb);
        #pragma unroll
        for (int i = 0; i < 4; ++i) {
            const int row = ar + i * 16 + a;
            uint2 w;
            w.x = pack2((acc[i][j][0] + bj.x) * s, (acc[i][j][1] + bj.y) * s);
            w.y = pack2((acc[i][j][2] + bj.z) * s, (acc[i][j][3] + bj.w) * s);
            *(uint2*)&Cs[row * 68 + (cb >> 1)] = w;
        }
    }
    __syncthreads();
    #pragma unroll
    for (int p = 0; p < MT / 16; ++p) {
        const int rowX = (MT == 128) ? ((t >> 2) + (p & 1) * 64) : (t >> 2);
        const int c2X  = (MT == 128) ? ((t & 3) * 4 + (p >> 1) * 16)
                                     : ((t & 3) * 4 + p * 16);
        uint4 w = *(const uint4*)&Cs[rowX * 68 + c2X];
        *(uint4*)&outB[(size_t)(row0 + rowX) * N + col0 + c2X * 2] = w;
    }
}

// ---------------------------------------------------------------------------
// MFMA flash attention (R9/R11 structure — plateaued ~68 us; K staged via LDS
// w/ register double-buffering; direct-global K lost twice R5/R10).
// bf16 qkv (Q pre-scaled by QSCALE), K-SPLIT x2, block = (b,h) x 128 q x
// half keys, 4 waves x 32 q. NO-MAX softmax: p = exp2(s), truncating bf16
// pack. l via MFMA ones-row (VtT rows 64..79, loop-invariant frags hoisted).
// XCD-SWIZZLE: v = (bid&7)*128 + bid>>3 (FETCH 71.7 -> 16.4 MB, R11).
// Outputs unnormalized O (bf16) + l (f32); attn_merge combines halves.
// market vol: softmax-shift-invariant -> omitted.
// ---------------------------------------------------------------------------
__global__ __launch_bounds__(256) void attn_mfma(
    const u16* __restrict__ qkv, u16* __restrict__ Oun, float* __restrict__ lbuf)
{
    const int bid  = blockIdx.x;     // 1024 = 2 halves x 512
    const int v_   = ((bid & 7) << 7) | (bid >> 3);   // XCD-major swizzle
    const int half = v_ >> 9;
    const int rest = v_ & 511;
    const int qt   = rest & 15;
    const int bh   = rest >> 4;
    const int h    = bh & 15;
    const int b    = bh >> 4;
    const int qb0  = qt * 128;

    const int t    = threadIdx.x;
    const int wave = t >> 6;
    const int lane = t & 63;
    const int a    = lane & 15;
    const int g    = lane >> 4;

    __shared__ __align__(16) u16 Kt[64 * 72];         // [key][d]
    __shared__ __align__(16) u16 VtT[80 * 72];        // [d][key]; 64..79 = l-rows
    __shared__ __align__(16) u16 Pl[4 * 2 * 16 * 72]; // [wave][q2][q][key]

    // one-time init of the l-row block: row 64 = 1.0 (bf16), rows 65..79 = 0
    for (int idx = t; idx < 16 * 36; idx += 256) {
        const int r = idx / 36;
        const int w = idx - r * 36;
        ((unsigned*)VtT)[(64 + r) * 36 + w] = (r == 0) ? 0x3F803F80u : 0u;
    }

    bf16x8 qf[2][2];
    #pragma unroll
    for (int q2 = 0; q2 < 2; ++q2) {
        const u16* qrow = qkv + (size_t)(b * L_ + qb0 + wave * 32 + q2 * 16 + a) * E3D
                        + h * DH_;
        #pragma unroll
        for (int c = 0; c < 2; ++c)
            qf[q2][c] = *(const bf16x8*)(qrow + c * 32 + g * 8);
    }

    __syncthreads();   // publish l-rows for the hoisted frag reads
    bf16x8 onesf[2];   // loop-invariant ones-row A-frags (rows 64..79 fixed)
    #pragma unroll
    for (int c = 0; c < 2; ++c)
        onesf[c] = *(const bf16x8*)&VtT[(64 + a) * 72 + c * 32 + g * 8];

    f32x4 o[2][4];
    f32x4 l4[2];
    #pragma unroll
    for (int q2 = 0; q2 < 2; ++q2) {
        #pragma unroll
        for (int dt = 0; dt < 4; ++dt)
            o[q2][dt] = (f32x4){0.f, 0.f, 0.f, 0.f};
        l4[q2] = (f32x4){0.f, 0.f, 0.f, 0.f};
    }

    const int krow = t >> 2;            // 0..63
    const int kseg = (t & 3) * 16;      // u16 offset in key row
    const int vu   = t >> 3;            // 0..31: key pair (2u, 2u+1)
    const int vc8  = (t & 7) * 8;       // d offset
    const int vj0  = t & 7;             // write stagger (read-only idx: OK)

    const u16* kbase = qkv + (size_t)(b * L_) * E3D + D_ + h * DH_;
    const u16* vbase = qkv + (size_t)(b * L_) * E3D + 2 * D_ + h * DH_;

    const int k_lo = half * (L_ / 2);
    const int k_hi = k_lo + L_ / 2;

    // prologue: prefetch first tile into registers
    uint4 kx0, kx1, va, vb;
    {
        const u16* kr = kbase + (size_t)(k_lo + krow) * E3D + kseg;
        kx0 = *(const uint4*)kr;
        kx1 = *(const uint4*)(kr + 8);
        const u16* vr = vbase + (size_t)(k_lo + 2 * vu) * E3D + vc8;
        va = *(const uint4*)vr;
        vb = *(const uint4*)(vr + E3D);
    }

    for (int k0 = k_lo; k0 < k_hi; k0 += 64) {
        __syncthreads();   // prior iteration's Kt/VtT reads complete

        // ---- stage K/V tiles from prefetched registers ----
        *(uint4*)&Kt[krow * 72 + kseg]     = kx0;
        *(uint4*)&Kt[krow * 72 + kseg + 8] = kx1;
        {
            const unsigned av[4] = {va.x, va.y, va.z, va.w};
            const unsigned bv[4] = {vb.x, vb.y, vb.z, vb.w};
            unsigned* Vw = (unsigned*)VtT;
            #pragma unroll
            for (int i = 0; i < 8; ++i) {
                const int j = (i + vj0) & 7;
                const unsigned xa = av[j >> 1], xb = bv[j >> 1];
                const unsigned v = (j & 1) ? ((xa >> 16) | (xb & 0xffff0000u))
                                           : ((xa & 0xffffu) | (xb << 16));
                Vw[(vc8 + j) * 36 + vu] = v;
            }
        }
        __syncthreads();

        // ---- prefetch next tile (covered by this iteration's compute) ----
        if (k0 + 64 < k_hi) {
            const u16* kr = kbase + (size_t)(k0 + 64 + krow) * E3D + kseg;
            kx0 = *(const uint4*)kr;
            kx1 = *(const uint4*)(kr + 8);
            const u16* vr = vbase + (size_t)(k0 + 64 + 2 * vu) * E3D + vc8;
            va = *(const uint4*)vr;
            vb = *(const uint4*)(vr + E3D);
        }

        // ---- S^T = K·Q^T ----
        f32x4 s[2][4];
        #pragma unroll
        for (int q2 = 0; q2 < 2; ++q2)
            #pragma unroll
            for (int kt = 0; kt < 4; ++kt)
                s[q2][kt] = (f32x4){0.f, 0.f, 0.f, 0.f};
        #pragma unroll
        for (int kt = 0; kt < 4; ++kt) {
            bf16x8 kf0 = *(const bf16x8*)&Kt[(kt * 16 + a) * 72 + g * 8];
            bf16x8 kf1 = *(const bf16x8*)&Kt[(kt * 16 + a) * 72 + 32 + g * 8];
            #pragma unroll
            for (int q2 = 0; q2 < 2; ++q2) {
                s[q2][kt] = __builtin_amdgcn_mfma_f32_16x16x32_bf16(kf0, qf[q2][0], s[q2][kt], 0, 0, 0);
                s[q2][kt] = __builtin_amdgcn_mfma_f32_16x16x32_bf16(kf1, qf[q2][1], s[q2][kt], 0, 0, 0);
            }
        }

        // ---- no-max softmax: p = exp2(s); truncating pack to wave-priv LDS
        #pragma unroll
        for (int q2 = 0; q2 < 2; ++q2) {
            unsigned* Pw = (unsigned*)&Pl[(wave * 2 + q2) * (16 * 72)];
            #pragma unroll
            for (int kt = 0; kt < 4; ++kt) {
                const float p0 = __builtin_amdgcn_exp2f(s[q2][kt][0]);
                const float p1 = __builtin_amdgcn_exp2f(s[q2][kt][1]);
                const float p2 = __builtin_amdgcn_exp2f(s[q2][kt][2]);
                const float p3 = __builtin_amdgcn_exp2f(s[q2][kt][3]);
                uint2 w;
                w.x = pack2t(p0, p1);
                w.y = pack2t(p2, p3);
                *(uint2*)&Pw[a * 36 + kt * 8 + g * 2] = w;
            }
        }
        // no barrier: Pl is wave-private, ds ordering via lgkmcnt

        // ---- PV: O^T += V^T · P^T ; l += ones-row · P^T ----
        #pragma unroll
        for (int c = 0; c < 2; ++c) {
            bf16x8 pf[2];
            #pragma unroll
            for (int q2 = 0; q2 < 2; ++q2)
                pf[q2] = *(const bf16x8*)&Pl[(wave * 2 + q2) * (16 * 72) + a * 72 + c * 32 + g * 8];
            #pragma unroll
            for (int dt = 0; dt < 4; ++dt) {
                bf16x8 vf = *(const bf16x8*)&VtT[(dt * 16 + a) * 72 + c * 32 + g * 8];
                #pragma unroll
                for (int q2 = 0; q2 < 2; ++q2)
                    o[q2][dt] = __builtin_amdgcn_mfma_f32_16x16x32_bf16(vf, pf[q2], o[q2][dt], 0, 0, 0);
            }
            #pragma unroll
            for (int q2 = 0; q2 < 2; ++q2)
                l4[q2] = __builtin_amdgcn_mfma_f32_16x16x32_bf16(onesf[c], pf[q2], l4[q2], 0, 0, 0);
        }
    }

    // ---- epilogue: unnormalized O (bf16, coalesced) + l (fp32) ----
    #pragma unroll
    for (int q2 = 0; q2 < 2; ++q2) {
        const int qrow = qb0 + wave * 32 + q2 * 16 + a;
        const size_t row = (size_t)(b * L_ + qrow);
        // l = l4[q2][0] on g==0 lanes (D-row 0 of the ones-tile)
        if (g == 0)
            lbuf[(size_t)half * 65536 + row * 16 + h] = l4[q2][0];
        u16* cp = Oun + (size_t)half * 4096 * 1024 + row * D_ + h * DH_;
        #pragma unroll
        for (int dt = 0; dt < 4; ++dt) {
            uint2 w;
            w.x = pack2(o[q2][dt][0], o[q2][dt][1]);
            w.y = pack2(o[q2][dt][2], o[q2][dt][3]);
            *(uint2*)&cp[dt * 16 + g * 4] = w;
        }
    }
}

// ---------------------------------------------------------------------------
// merge the two K-split halves: ctx = (O0 + O1) / (l0 + l1)
// ---------------------------------------------------------------------------
__global__ __launch_bounds__(256) void attn_merge(
    const u16* __restrict__ Oun, const float* __restrict__ lbuf,
    u16* __restrict__ ctx)
{
    const int row = blockIdx.x;         // 4096
    const int t   = threadIdx.x;
    const int col = t * 4;
    const int h   = col >> 6;
    const float inv = 1.f / (lbuf[(size_t)row * 16 + h] +
                             lbuf[(size_t)65536 + row * 16 + h]);
    const size_t base = (size_t)row * D_ + col;
    uint2 w0 = *(const uint2*)&Oun[base];
    uint2 w1 = *(const uint2*)&Oun[(size_t)4096 * 1024 + base];
    float f0 = (bf2f((u16)(w0.x & 0xffff)) + bf2f((u16)(w1.x & 0xffff))) * inv;
    float f1 = (bf2f((u16)(w0.x >> 16))    + bf2f((u16)(w1.x >> 16)))    * inv;
    float f2 = (bf2f((u16)(w0.y & 0xffff)) + bf2f((u16)(w1.y & 0xffff))) * inv;
    float f3 = (bf2f((u16)(w0.y >> 16))    + bf2f((u16)(w1.y >> 16)))    * inv;
    uint2 w;
    w.x = pack2(f0, f1);
    w.y = pack2(f2, f3);
    *(uint2*)&ctx[base] = w;
}

// ---------------------------------------------------------------------------
// Residual + LayerNorm: out = LN(x + attended), attended in bf16.
// ---------------------------------------------------------------------------
__global__ __launch_bounds__(256) void ln_rows(
    const float* __restrict__ x, const u16* __restrict__ att,
    const float* __restrict__ gamma, const float* __restrict__ beta,
    float* __restrict__ out)
{
    const int row = blockIdx.x;
    const int t = threadIdx.x;
    const size_t base = (size_t)row * D_ + t * 4;

    float4 v = *(const float4*)(x + base);
    uint2 aw = *(const uint2*)(att + base);
    v.x += bf2f((u16)(aw.x & 0xffff));
    v.y += bf2f((u16)(aw.x >> 16));
    v.z += bf2f((u16)(aw.y & 0xffff));
    v.w += bf2f((u16)(aw.y >> 16));

    float s  = v.x + v.y + v.z + v.w;
    float s2 = v.x * v.x + v.y * v.y + v.z * v.z + v.w * v.w;
    #pragma unroll
    for (int off = 32; off > 0; off >>= 1) {
        s  += __shfl_down(s, off);
        s2 += __shfl_down(s2, off);
    }
    __shared__ float red[4], red2[4];
    const int wid = t >> 6, lid = t & 63;
    if (lid == 0) { red[wid] = s; red2[wid] = s2; }
    __syncthreads();
    if (t == 0) {
        float aa = 0.f, b2 = 0.f;
        #pragma unroll
        for (int i = 0; i < 4; ++i) { aa += red[i]; b2 += red2[i]; }
        red[0] = aa; red2[0] = b2;
    }
    __syncthreads();
    const float mu   = red[0] * (1.f / D_);
    const float var  = red2[0] * (1.f / D_) - mu * mu;
    const float rstd = rsqrtf(var + LN_EPS);

    float4 gm = *(const float4*)(gamma + t * 4);
    float4 bt = *(const float4*)(beta + t * 4);
    float4 oo;
    oo.x = (v.x - mu) * rstd * gm.x + bt.x;
    oo.y = (v.y - mu) * rstd * gm.y + bt.y;
    oo.z = (v.z - mu) * rstd * gm.z + bt.z;
    oo.w = (v.w - mu) * rstd * gm.w + bt.w;
    *(float4*)(out + base) = oo;
}

// ---------------------------------------------------------------------------
extern "C" void kernel_launch(void* const* d_in, const int* in_sizes, int n_in,
                              void* d_out, int out_size, void* d_ws, size_t ws_size,
                              hipStream_t stream)
{
    const float* x      = (const float*)d_in[0];
    // d_in[1] = market_info: softmax-shift-invariant -> unused
    const float* in_w   = (const float*)d_in[2];
    const float* in_b   = (const float*)d_in[3];
    const float* out_w  = (const float*)d_in[4];
    const float* out_b  = (const float*)d_in[5];
    const float* gamma  = (const float*)d_in[6];
    const float* beta   = (const float*)d_in[7];
    float* out = (float*)d_out;

    // workspace layout (<= 64 MiB):
    char* ws   = (char*)d_ws;
    u16*  qkvb = (u16*)ws;                         // 24 MiB
    u16*  Oun  = (u16*)(ws + 25165824);            // 16 MiB (2 x 8 MiB bf16)
    u16*  po   = (u16*)(ws + 25165824);            //  8 MiB (aliases Oun; dead)
    u16*  ctxb = (u16*)(ws + 41943040);            //  8 MiB
    u16*  xb   = (u16*)(ws + 50331648);            //  8 MiB [lb aliases after]
    float* lb  = (float*)(ws + 50331648);          // 512 KiB (xb dead by attn)
    u16*  iwb  = (u16*)(ws + 58720256);            //  6 MiB
    u16*  owb  = (u16*)(ws + 65011712);            //  2 MiB

    dim3 blk(256);
    cvt_all<<<dim3(4096), blk, 0, stream>>>(x, in_w, out_w, xb, iwb, owb);

    // QKV: bf16 out, Q cols pre-scaled by QSCALE. 64x128 tile ->
    // grid 24x64 = 1536 blocks = 6 blk/CU (128-tile gave only 3/CU).
    gemm_bf16<64><<<dim3(E3D / 128, (B_ * L_) / 64), blk, 0, stream>>>(
        xb, iwb, in_b, qkvb, B_ * L_, E3D, D_, D_);

    attn_mfma<<<dim3(2 * B_ * H_ * (L_ / 128)), blk, 0, stream>>>(qkvb, Oun, lb);
    attn_merge<<<dim3(B_ * L_), blk, 0, stream>>>(Oun, lb, ctxb);

    // out-proj + bias, bf16 out (residual folded into ln_rows). 64x128 tile.
    gemm_bf16<64><<<dim3(D_ / 128, (B_ * L_) / 64), blk, 0, stream>>>(
        ctxb, owb, out_b, po, B_ * L_, D_, D_, 0);

    ln_rows<<<dim3(B_ * L_), blk, 0, stream>>>(x, po, gamma, beta, out);
}

// Round 13
// 208.754 us; speedup vs baseline: 1.1096x; 1.1096x over previous
//
#include <hip/hip_runtime.h>
#include <math.h>

#define B_  2
#define L_  2048
#define D_  1024
#define H_  16
#define DH_ 64
#define E3D 3072
#define LN_EPS 1e-5f

typedef unsigned short u16;
typedef __attribute__((ext_vector_type(8))) short bf16x8;
typedef __attribute__((ext_vector_type(4))) float f32x4;

// pack two fp32 -> packed bf16 pair (round-half-up) via v_perm_b32
__device__ inline unsigned pack2(float lo, float hi) {
    unsigned a = __builtin_bit_cast(unsigned, lo) + 0x8000u;
    unsigned b = __builtin_bit_cast(unsigned, hi) + 0x8000u;
    return __builtin_amdgcn_perm(b, a, 0x07060302);
}
// truncating variant (1 op): used ONLY for P in the attention softmax.
// p feeds numerator (PV) and denominator (ones-row l) with the same bits,
// so the downward truncation bias cancels to first order in O = PV/l.
__device__ inline unsigned pack2t(float lo, float hi) {
    return __builtin_amdgcn_perm(__builtin_bit_cast(unsigned, hi),
                                 __builtin_bit_cast(unsigned, lo), 0x07060302);
}
__device__ inline float bf2f(u16 v) {
    return __builtin_bit_cast(float, (unsigned)v << 16);
}
__device__ inline void async16(const void* g, void* l) {
    __builtin_amdgcn_global_load_lds(
        (const __attribute__((address_space(1))) unsigned*)g,
        (__attribute__((address_space(3))) unsigned*)l, 16, 0, 0);
}

// log2(e) folded into Q scale so softmax uses raw v_exp_f32 (exp2)
#define QSCALE (0.125f * 1.44269504088896f)

// ---------------------------------------------------------------------------
// fused f32 -> bf16 conversion of x (2048 blk) / in_w (1536 blk) / out_w (512)
// ---------------------------------------------------------------------------
__global__ __launch_bounds__(256) void cvt_all(
    const float* __restrict__ x, const float* __restrict__ iw,
    const float* __restrict__ ow, u16* __restrict__ xb,
    u16* __restrict__ iwb, u16* __restrict__ owb)
{
    const int bid = blockIdx.x;
    const float* src; u16* dst; int base;
    if (bid < 2048)      { src = x;  dst = xb;  base = bid * 2048; }
    else if (bid < 3584) { src = iw; dst = iwb; base = (bid - 2048) * 2048; }
    else                 { src = ow; dst = owb; base = (bid - 3584) * 2048; }
    const int i = base + threadIdx.x * 8;
    float4 v0 = *(const float4*)(src + i);
    float4 v1 = *(const float4*)(src + i + 4);
    uint4 w;
    w.x = pack2(v0.x, v0.y); w.y = pack2(v0.z, v0.w);
    w.z = pack2(v1.x, v1.y); w.w = pack2(v1.z, v1.w);
    *(uint4*)(dst + i) = w;
}

// ---------------------------------------------------------------------------
// bf16 MFMA NT-GEMM: C = A * W^T + bias, bf16 out.  A: MxK, W: NxK (bf16).
// MT = M-tile: 128 (QKV: 3 blk/CU — R12 showed MT=64 here regresses, W
// re-staging doubles) or 64 (out-proj: 2 blk/CU vs 1). N-tile fixed 128.
// BK=64 via DUAL 32-col sub-tiles (As0/As1, Ws0/Ws1 — each unpadded 128x32,
// same staging lane-map and conflict-free 2-way frag reads as BK=32):
// halves the s_barrier + vmcnt/lgkmcnt drains (the dominant GEMM stall, m98).
// Operands swapped (mfma(wf, af)) -> lane owns 4 consecutive cols.
// Epilogue: bf16 -> LDS (68-word padded rows) -> lane-contiguous uint4 stores.
// NOTE: acc[][] only indexed with compile-time constants (R6 scratch lesson).
// cols < qlimit scaled by QSCALE (attention scale + log2e folded).
// ---------------------------------------------------------------------------
template<int MT>
__global__ __launch_bounds__(256) void gemm_bf16(
    const u16* __restrict__ A, const u16* __restrict__ W,
    const float* __restrict__ bias, u16* __restrict__ outB,
    int M, int N, int K, int qlimit)
{
    constexpr int WC  = (MT == 128) ? 4 : 2;        // col subtiles per wave
    constexpr int STG = (MT + 128) * 64 * 2;        // staging bytes (4 subtiles)
    constexpr int EPI = MT * 68 * 4;                // epilogue bytes
    constexpr int SMEMB = (STG > EPI) ? STG : EPI;  // 128:34816, 64:24576
    __shared__ __align__(16) char smem[SMEMB];
    u16* As0 = (u16*)smem;            // MT x 32  (k 0..31 of the 64-chunk)
    u16* As1 = As0 + MT * 32;         // MT x 32  (k 32..63)
    u16* Ws0 = As1 + MT * 32;         // 128 x 32
    u16* Ws1 = Ws0 + 128 * 32;        // 128 x 32

    const int t    = threadIdx.x;
    const int wave = t >> 6;
    const int lane = t & 63;
    const int a    = lane & 15;
    const int g    = lane >> 4;
    const int row0 = blockIdx.y * MT;
    const int col0 = blockIdx.x * 128;

    // staging map (per 32-col sub-tile): wave stages MT/4 rows of A, 32 of W;
    // lane -> row = base + (lane>>2), col-seg = (lane&3)*8  (16B per lane)
    const int srowA = wave * (MT / 4) + (lane >> 2);
    const int srowW = wave * 32 + (lane >> 2);
    const int sseg  = (lane & 3) * 8;
    const u16* Ag = A + (size_t)(row0 + srowA) * K + sseg;
    const u16* Wg = W + (size_t)(col0 + srowW) * K + sseg;
    u16* As0W = &As0[wave * (MT / 4) * 32];
    u16* As1W = &As1[wave * (MT / 4) * 32];
    u16* Ws0W = &Ws0[wave * 32 * 32];
    u16* Ws1W = &Ws1[wave * 32 * 32];

    f32x4 acc[4][WC];
    #pragma unroll
    for (int i = 0; i < 4; ++i)
        #pragma unroll
        for (int j = 0; j < WC; ++j)
            acc[i][j] = (f32x4){0.f, 0.f, 0.f, 0.f};

    const int ar = (MT == 128) ? (wave & 1) * 64 : 0;
    const int wc = (MT == 128) ? (wave >> 1) * 64 : wave * 32;

    for (int kt = 0; kt < K; kt += 64) {
        __syncthreads();
        if (MT == 128) {
            async16(Ag + kt,                       As0W);
            async16(Ag + (size_t)16 * K + kt,      As0W + 16 * 32);
            async16(Ag + kt + 32,                  As1W);
            async16(Ag + (size_t)16 * K + kt + 32, As1W + 16 * 32);
        } else {
            async16(Ag + kt,      As0W);   // 16 rows/wave: one instr/sub-tile
            async16(Ag + kt + 32, As1W);
        }
        async16(Wg + kt,                       Ws0W);
        async16(Wg + (size_t)16 * K + kt,      Ws0W + 16 * 32);
        async16(Wg + kt + 32,                  Ws1W);
        async16(Wg + (size_t)16 * K + kt + 32, Ws1W + 16 * 32);
        __syncthreads();

        bf16x8 af[4][2], wf[WC][2];
        #pragma unroll
        for (int i = 0; i < 4; ++i) {
            af[i][0] = *(const bf16x8*)&As0[(ar + i * 16 + a) * 32 + g * 8];
            af[i][1] = *(const bf16x8*)&As1[(ar + i * 16 + a) * 32 + g * 8];
        }
        #pragma unroll
        for (int j = 0; j < WC; ++j) {
            wf[j][0] = *(const bf16x8*)&Ws0[(wc + j * 16 + a) * 32 + g * 8];
            wf[j][1] = *(const bf16x8*)&Ws1[(wc + j * 16 + a) * 32 + g * 8];
        }
        #pragma unroll
        for (int i = 0; i < 4; ++i)
            #pragma unroll
            for (int j = 0; j < WC; ++j) {
                acc[i][j] = __builtin_amdgcn_mfma_f32_16x16x32_bf16(
                    wf[j][0], af[i][0], acc[i][j], 0, 0, 0);
                acc[i][j] = __builtin_amdgcn_mfma_f32_16x16x32_bf16(
                    wf[j][1], af[i][1], acc[i][j], 0, 0, 0);
            }
    }

    // ---- epilogue: acc -> LDS (constant indices only) -> coalesced stores
    const float s = (col0 < qlimit) ? QSCALE : 1.0f;
    __syncthreads();                      // staging reads done; reuse smem
    unsigned* Cs = (unsigned*)smem;       // MT rows x 68 words (64 data + pad)
    #pragma unroll
    for (int j = 0; j < WC; ++j) {
        const int cb = wc + j * 16 + g * 4;
        const float4 bj = *(const float4*)(bias + col0 + cb);
        #pragma unroll
        for (int i = 0; i < 4; ++i) {
            const int row = ar + i * 16 + a;
            uint2 w;
            w.x = pack2((acc[i][j][0] + bj.x) * s, (acc[i][j][1] + bj.y) * s);
            w.y = pack2((acc[i][j][2] + bj.z) * s, (acc[i][j][3] + bj.w) * s);
            *(uint2*)&Cs[row * 68 + (cb >> 1)] = w;
        }
    }
    __syncthreads();
    #pragma unroll
    for (int p = 0; p < MT / 16; ++p) {
        const int rowX = (MT == 128) ? ((t >> 2) + (p & 1) * 64) : (t >> 2);
        const int c2X  = (MT == 128) ? ((t & 3) * 4 + (p >> 1) * 16)
                                     : ((t & 3) * 4 + p * 16);
        uint4 w = *(const uint4*)&Cs[rowX * 68 + c2X];
        *(uint4*)&outB[(size_t)(row0 + rowX) * N + col0 + c2X * 2] = w;
    }
}

// ---------------------------------------------------------------------------
// MFMA flash attention (R9/R11 structure — plateaued ~68 us; K staged via LDS
// w/ register double-buffering; direct-global K lost twice R5/R10).
// bf16 qkv (Q pre-scaled by QSCALE), K-SPLIT x2, block = (b,h) x 128 q x
// half keys, 4 waves x 32 q. NO-MAX softmax: p = exp2(s), truncating bf16
// pack. l via MFMA ones-row (VtT rows 64..79, loop-invariant frags hoisted).
// XCD-SWIZZLE: v = (bid&7)*128 + bid>>3 (FETCH 71.7 -> 16.4 MB, R11).
// Outputs unnormalized O (bf16) + l (f32); attn_merge combines halves.
// market vol: softmax-shift-invariant -> omitted.
// ---------------------------------------------------------------------------
__global__ __launch_bounds__(256) void attn_mfma(
    const u16* __restrict__ qkv, u16* __restrict__ Oun, float* __restrict__ lbuf)
{
    const int bid  = blockIdx.x;     // 1024 = 2 halves x 512
    const int v_   = ((bid & 7) << 7) | (bid >> 3);   // XCD-major swizzle
    const int half = v_ >> 9;
    const int rest = v_ & 511;
    const int qt   = rest & 15;
    const int bh   = rest >> 4;
    const int h    = bh & 15;
    const int b    = bh >> 4;
    const int qb0  = qt * 128;

    const int t    = threadIdx.x;
    const int wave = t >> 6;
    const int lane = t & 63;
    const int a    = lane & 15;
    const int g    = lane >> 4;

    __shared__ __align__(16) u16 Kt[64 * 72];         // [key][d]
    __shared__ __align__(16) u16 VtT[80 * 72];        // [d][key]; 64..79 = l-rows
    __shared__ __align__(16) u16 Pl[4 * 2 * 16 * 72]; // [wave][q2][q][key]

    // one-time init of the l-row block: row 64 = 1.0 (bf16), rows 65..79 = 0
    for (int idx = t; idx < 16 * 36; idx += 256) {
        const int r = idx / 36;
        const int w = idx - r * 36;
        ((unsigned*)VtT)[(64 + r) * 36 + w] = (r == 0) ? 0x3F803F80u : 0u;
    }

    bf16x8 qf[2][2];
    #pragma unroll
    for (int q2 = 0; q2 < 2; ++q2) {
        const u16* qrow = qkv + (size_t)(b * L_ + qb0 + wave * 32 + q2 * 16 + a) * E3D
                        + h * DH_;
        #pragma unroll
        for (int c = 0; c < 2; ++c)
            qf[q2][c] = *(const bf16x8*)(qrow + c * 32 + g * 8);
    }

    __syncthreads();   // publish l-rows for the hoisted frag reads
    bf16x8 onesf[2];   // loop-invariant ones-row A-frags (rows 64..79 fixed)
    #pragma unroll
    for (int c = 0; c < 2; ++c)
        onesf[c] = *(const bf16x8*)&VtT[(64 + a) * 72 + c * 32 + g * 8];

    f32x4 o[2][4];
    f32x4 l4[2];
    #pragma unroll
    for (int q2 = 0; q2 < 2; ++q2) {
        #pragma unroll
        for (int dt = 0; dt < 4; ++dt)
            o[q2][dt] = (f32x4){0.f, 0.f, 0.f, 0.f};
        l4[q2] = (f32x4){0.f, 0.f, 0.f, 0.f};
    }

    const int krow = t >> 2;            // 0..63
    const int kseg = (t & 3) * 16;      // u16 offset in key row
    const int vu   = t >> 3;            // 0..31: key pair (2u, 2u+1)
    const int vc8  = (t & 7) * 8;       // d offset
    const int vj0  = t & 7;             // write stagger (read-only idx: OK)

    const u16* kbase = qkv + (size_t)(b * L_) * E3D + D_ + h * DH_;
    const u16* vbase = qkv + (size_t)(b * L_) * E3D + 2 * D_ + h * DH_;

    const int k_lo = half * (L_ / 2);
    const int k_hi = k_lo + L_ / 2;

    // prologue: prefetch first tile into registers
    uint4 kx0, kx1, va, vb;
    {
        const u16* kr = kbase + (size_t)(k_lo + krow) * E3D + kseg;
        kx0 = *(const uint4*)kr;
        kx1 = *(const uint4*)(kr + 8);
        const u16* vr = vbase + (size_t)(k_lo + 2 * vu) * E3D + vc8;
        va = *(const uint4*)vr;
        vb = *(const uint4*)(vr + E3D);
    }

    for (int k0 = k_lo; k0 < k_hi; k0 += 64) {
        __syncthreads();   // prior iteration's Kt/VtT reads complete

        // ---- stage K/V tiles from prefetched registers ----
        *(uint4*)&Kt[krow * 72 + kseg]     = kx0;
        *(uint4*)&Kt[krow * 72 + kseg + 8] = kx1;
        {
            const unsigned av[4] = {va.x, va.y, va.z, va.w};
            const unsigned bv[4] = {vb.x, vb.y, vb.z, vb.w};
            unsigned* Vw = (unsigned*)VtT;
            #pragma unroll
            for (int i = 0; i < 8; ++i) {
                const int j = (i + vj0) & 7;
                const unsigned xa = av[j >> 1], xb = bv[j >> 1];
                const unsigned v = (j & 1) ? ((xa >> 16) | (xb & 0xffff0000u))
                                           : ((xa & 0xffffu) | (xb << 16));
                Vw[(vc8 + j) * 36 + vu] = v;
            }
        }
        __syncthreads();

        // ---- prefetch next tile (covered by this iteration's compute) ----
        if (k0 + 64 < k_hi) {
            const u16* kr = kbase + (size_t)(k0 + 64 + krow) * E3D + kseg;
            kx0 = *(const uint4*)kr;
            kx1 = *(const uint4*)(kr + 8);
            const u16* vr = vbase + (size_t)(k0 + 64 + 2 * vu) * E3D + vc8;
            va = *(const uint4*)vr;
            vb = *(const uint4*)(vr + E3D);
        }

        // ---- S^T = K·Q^T ----
        f32x4 s[2][4];
        #pragma unroll
        for (int q2 = 0; q2 < 2; ++q2)
            #pragma unroll
            for (int kt = 0; kt < 4; ++kt)
                s[q2][kt] = (f32x4){0.f, 0.f, 0.f, 0.f};
        #pragma unroll
        for (int kt = 0; kt < 4; ++kt) {
            bf16x8 kf0 = *(const bf16x8*)&Kt[(kt * 16 + a) * 72 + g * 8];
            bf16x8 kf1 = *(const bf16x8*)&Kt[(kt * 16 + a) * 72 + 32 + g * 8];
            #pragma unroll
            for (int q2 = 0; q2 < 2; ++q2) {
                s[q2][kt] = __builtin_amdgcn_mfma_f32_16x16x32_bf16(kf0, qf[q2][0], s[q2][kt], 0, 0, 0);
                s[q2][kt] = __builtin_amdgcn_mfma_f32_16x16x32_bf16(kf1, qf[q2][1], s[q2][kt], 0, 0, 0);
            }
        }

        // ---- no-max softmax: p = exp2(s); truncating pack to wave-priv LDS
        #pragma unroll
        for (int q2 = 0; q2 < 2; ++q2) {
            unsigned* Pw = (unsigned*)&Pl[(wave * 2 + q2) * (16 * 72)];
            #pragma unroll
            for (int kt = 0; kt < 4; ++kt) {
                const float p0 = __builtin_amdgcn_exp2f(s[q2][kt][0]);
                const float p1 = __builtin_amdgcn_exp2f(s[q2][kt][1]);
                const float p2 = __builtin_amdgcn_exp2f(s[q2][kt][2]);
                const float p3 = __builtin_amdgcn_exp2f(s[q2][kt][3]);
                uint2 w;
                w.x = pack2t(p0, p1);
                w.y = pack2t(p2, p3);
                *(uint2*)&Pw[a * 36 + kt * 8 + g * 2] = w;
            }
        }
        // no barrier: Pl is wave-private, ds ordering via lgkmcnt

        // ---- PV: O^T += V^T · P^T ; l += ones-row · P^T ----
        #pragma unroll
        for (int c = 0; c < 2; ++c) {
            bf16x8 pf[2];
            #pragma unroll
            for (int q2 = 0; q2 < 2; ++q2)
                pf[q2] = *(const bf16x8*)&Pl[(wave * 2 + q2) * (16 * 72) + a * 72 + c * 32 + g * 8];
            #pragma unroll
            for (int dt = 0; dt < 4; ++dt) {
                bf16x8 vf = *(const bf16x8*)&VtT[(dt * 16 + a) * 72 + c * 32 + g * 8];
                #pragma unroll
                for (int q2 = 0; q2 < 2; ++q2)
                    o[q2][dt] = __builtin_amdgcn_mfma_f32_16x16x32_bf16(vf, pf[q2], o[q2][dt], 0, 0, 0);
            }
            #pragma unroll
            for (int q2 = 0; q2 < 2; ++q2)
                l4[q2] = __builtin_amdgcn_mfma_f32_16x16x32_bf16(onesf[c], pf[q2], l4[q2], 0, 0, 0);
        }
    }

    // ---- epilogue: unnormalized O (bf16, coalesced) + l (fp32) ----
    #pragma unroll
    for (int q2 = 0; q2 < 2; ++q2) {
        const int qrow = qb0 + wave * 32 + q2 * 16 + a;
        const size_t row = (size_t)(b * L_ + qrow);
        // l = l4[q2][0] on g==0 lanes (D-row 0 of the ones-tile)
        if (g == 0)
            lbuf[(size_t)half * 65536 + row * 16 + h] = l4[q2][0];
        u16* cp = Oun + (size_t)half * 4096 * 1024 + row * D_ + h * DH_;
        #pragma unroll
        for (int dt = 0; dt < 4; ++dt) {
            uint2 w;
            w.x = pack2(o[q2][dt][0], o[q2][dt][1]);
            w.y = pack2(o[q2][dt][2], o[q2][dt][3]);
            *(uint2*)&cp[dt * 16 + g * 4] = w;
        }
    }
}

// ---------------------------------------------------------------------------
// merge the two K-split halves: ctx = (O0 + O1) / (l0 + l1)
// ---------------------------------------------------------------------------
__global__ __launch_bounds__(256) void attn_merge(
    const u16* __restrict__ Oun, const float* __restrict__ lbuf,
    u16* __restrict__ ctx)
{
    const int row = blockIdx.x;         // 4096
    const int t   = threadIdx.x;
    const int col = t * 4;
    const int h   = col >> 6;
    const float inv = 1.f / (lbuf[(size_t)row * 16 + h] +
                             lbuf[(size_t)65536 + row * 16 + h]);
    const size_t base = (size_t)row * D_ + col;
    uint2 w0 = *(const uint2*)&Oun[base];
    uint2 w1 = *(const uint2*)&Oun[(size_t)4096 * 1024 + base];
    float f0 = (bf2f((u16)(w0.x & 0xffff)) + bf2f((u16)(w1.x & 0xffff))) * inv;
    float f1 = (bf2f((u16)(w0.x >> 16))    + bf2f((u16)(w1.x >> 16)))    * inv;
    float f2 = (bf2f((u16)(w0.y & 0xffff)) + bf2f((u16)(w1.y & 0xffff))) * inv;
    float f3 = (bf2f((u16)(w0.y >> 16))    + bf2f((u16)(w1.y >> 16)))    * inv;
    uint2 w;
    w.x = pack2(f0, f1);
    w.y = pack2(f2, f3);
    *(uint2*)&ctx[base] = w;
}

// ---------------------------------------------------------------------------
// Residual + LayerNorm: out = LN(x + attended), attended in bf16.
// ---------------------------------------------------------------------------
__global__ __launch_bounds__(256) void ln_rows(
    const float* __restrict__ x, const u16* __restrict__ att,
    const float* __restrict__ gamma, const float* __restrict__ beta,
    float* __restrict__ out)
{
    const int row = blockIdx.x;
    const int t = threadIdx.x;
    const size_t base = (size_t)row * D_ + t * 4;

    float4 v = *(const float4*)(x + base);
    uint2 aw = *(const uint2*)(att + base);
    v.x += bf2f((u16)(aw.x & 0xffff));
    v.y += bf2f((u16)(aw.x >> 16));
    v.z += bf2f((u16)(aw.y & 0xffff));
    v.w += bf2f((u16)(aw.y >> 16));

    float s  = v.x + v.y + v.z + v.w;
    float s2 = v.x * v.x + v.y * v.y + v.z * v.z + v.w * v.w;
    #pragma unroll
    for (int off = 32; off > 0; off >>= 1) {
        s  += __shfl_down(s, off);
        s2 += __shfl_down(s2, off);
    }
    __shared__ float red[4], red2[4];
    const int wid = t >> 6, lid = t & 63;
    if (lid == 0) { red[wid] = s; red2[wid] = s2; }
    __syncthreads();
    if (t == 0) {
        float aa = 0.f, b2 = 0.f;
        #pragma unroll
        for (int i = 0; i < 4; ++i) { aa += red[i]; b2 += red2[i]; }
        red[0] = aa; red2[0] = b2;
    }
    __syncthreads();
    const float mu   = red[0] * (1.f / D_);
    const float var  = red2[0] * (1.f / D_) - mu * mu;
    const float rstd = rsqrtf(var + LN_EPS);

    float4 gm = *(const float4*)(gamma + t * 4);
    float4 bt = *(const float4*)(beta + t * 4);
    float4 oo;
    oo.x = (v.x - mu) * rstd * gm.x + bt.x;
    oo.y = (v.y - mu) * rstd * gm.y + bt.y;
    oo.z = (v.z - mu) * rstd * gm.z + bt.z;
    oo.w = (v.w - mu) * rstd * gm.w + bt.w;
    *(float4*)(out + base) = oo;
}

// ---------------------------------------------------------------------------
extern "C" void kernel_launch(void* const* d_in, const int* in_sizes, int n_in,
                              void* d_out, int out_size, void* d_ws, size_t ws_size,
                              hipStream_t stream)
{
    const float* x      = (const float*)d_in[0];
    // d_in[1] = market_info: softmax-shift-invariant -> unused
    const float* in_w   = (const float*)d_in[2];
    const float* in_b   = (const float*)d_in[3];
    const float* out_w  = (const float*)d_in[4];
    const float* out_b  = (const float*)d_in[5];
    const float* gamma  = (const float*)d_in[6];
    const float* beta   = (const float*)d_in[7];
    float* out = (float*)d_out;

    // workspace layout (<= 64 MiB):
    char* ws   = (char*)d_ws;
    u16*  qkvb = (u16*)ws;                         // 24 MiB
    u16*  Oun  = (u16*)(ws + 25165824);            // 16 MiB (2 x 8 MiB bf16)
    u16*  po   = (u16*)(ws + 25165824);            //  8 MiB (aliases Oun; dead)
    u16*  ctxb = (u16*)(ws + 41943040);            //  8 MiB
    u16*  xb   = (u16*)(ws + 50331648);            //  8 MiB [lb aliases after]
    float* lb  = (float*)(ws + 50331648);          // 512 KiB (xb dead by attn)
    u16*  iwb  = (u16*)(ws + 58720256);            //  6 MiB
    u16*  owb  = (u16*)(ws + 65011712);            //  2 MiB

    dim3 blk(256);
    cvt_all<<<dim3(4096), blk, 0, stream>>>(x, in_w, out_w, xb, iwb, owb);

    // QKV: bf16 out, Q cols pre-scaled by QSCALE. 128x128 tile (R12: MT=64
    // regressed here — W re-staging doubled), BK=64.
    gemm_bf16<128><<<dim3(E3D / 128, (B_ * L_) / 128), blk, 0, stream>>>(
        xb, iwb, in_b, qkvb, B_ * L_, E3D, D_, D_);

    attn_mfma<<<dim3(2 * B_ * H_ * (L_ / 128)), blk, 0, stream>>>(qkvb, Oun, lb);
    attn_merge<<<dim3(B_ * L_), blk, 0, stream>>>(Oun, lb, ctxb);

    // out-proj + bias, bf16 out (residual folded into ln_rows). 64x128 tile.
    gemm_bf16<64><<<dim3(D_ / 128, (B_ * L_) / 64), blk, 0, stream>>>(
        ctxb, owb, out_b, po, B_ * L_, D_, D_, 0);

    ln_rows<<<dim3(B_ * L_), blk, 0, stream>>>(x, po, gamma, beta, out);
}